// Round 1
// baseline (661.774 us; speedup 1.0000x reference)
//
#include <hip/hip_runtime.h>
#include <stdint.h>

#define DEV __device__ __forceinline__

typedef __attribute__((ext_vector_type(8))) short bf16x8;
typedef __attribute__((ext_vector_type(4))) float f32x4;

#define NTOT 2304

DEV unsigned short f2bf(float f) {
  union { float f; unsigned u; } c; c.f = f;
  return (unsigned short)((c.u + 0x7FFFu + ((c.u >> 16) & 1u)) >> 16);
}
DEV unsigned pack2(float lo, float hi) {
  return ((unsigned)f2bf(hi) << 16) | (unsigned)f2bf(lo);
}
DEV void gload_lds16(const void* g, void* l) {
  __builtin_amdgcn_global_load_lds(
      (const __attribute__((address_space(1))) unsigned int*)g,
      (__attribute__((address_space(3))) unsigned int*)l, 16, 0, 0);
}

// ---------------- RMS-modulated norm: out_bf16 = x * rsqrt(mean(x^2)+eps) * (1+scale) ----
__global__ __launch_bounds__(256) void k_modnorm(const float* __restrict__ X,
                                                 const float* __restrict__ scale,
                                                 short* __restrict__ out, int D, float eps) {
  int row = blockIdx.x;
  const float* x = X + (size_t)row * D;
  float ss = 0.f;
  for (int v = threadIdx.x * 4; v < D; v += 1024) {
    float4 a = *(const float4*)(x + v);
    ss += a.x * a.x + a.y * a.y + a.z * a.z + a.w * a.w;
  }
#pragma unroll
  for (int m = 1; m < 64; m <<= 1) ss += __shfl_xor(ss, m);
  __shared__ float red[4];
  if ((threadIdx.x & 63) == 0) red[threadIdx.x >> 6] = ss;
  __syncthreads();
  float tot = red[0] + red[1] + red[2] + red[3];
  float r = rsqrtf(tot / (float)D + eps);
  short* o = out + (size_t)row * D;
  for (int v = threadIdx.x * 4; v < D; v += 1024) {
    float4 a = *(const float4*)(x + v);
    float4 s = *(const float4*)(scale + v);
    uint2 pk;
    pk.x = pack2(a.x * r * (1.f + s.x), a.y * r * (1.f + s.y));
    pk.y = pack2(a.z * r * (1.f + s.z), a.w * r * (1.f + s.w));
    *(uint2*)(o + v) = pk;
  }
}

// ---------------- f32 -> bf16 convert ----------------
__global__ __launch_bounds__(256) void k_cvt(const float* __restrict__ in,
                                             short* __restrict__ out, int n4) {
  int stride = gridDim.x * blockDim.x;
  for (int i = blockIdx.x * blockDim.x + threadIdx.x; i < n4; i += stride) {
    float4 a = *(const float4*)(in + (size_t)i * 4);
    uint2 pk;
    pk.x = pack2(a.x, a.y);
    pk.y = pack2(a.z, a.w);
    *(uint2*)(out + (size_t)i * 4) = pk;
  }
}

// ---------------- C_f32[M][N] = A_bf16[M][K] @ B_bf16[N][K]^T + bias[N] ----------------
// BM=BN=128, BK=64, 4 waves each 64x64, global_load_lds w/ XOR-swizzled source.
__global__ __launch_bounds__(256) void k_gemm(const short* __restrict__ A,
                                              const short* __restrict__ B,
                                              const float* __restrict__ bias,
                                              float* __restrict__ C, int M, int N, int K) {
  __shared__ __align__(16) char As[16384];
  __shared__ __align__(16) char Bs[16384];
  const int tid = threadIdx.x;
  const int brow = blockIdx.y * 128, bcol = blockIdx.x * 128;
  const int w = tid >> 6, l = tid & 63;
  const int wr = (w >> 1) * 64, wc = (w & 1) * 64;
  const int lr = l & 15, lg = l >> 4;
  f32x4 acc[4][4];
#pragma unroll
  for (int m = 0; m < 4; ++m)
#pragma unroll
    for (int n = 0; n < 4; ++n) acc[m][n] = (f32x4){0.f, 0.f, 0.f, 0.f};
  for (int k0 = 0; k0 < K; k0 += 64) {
#pragma unroll
    for (int it = 0; it < 4; ++it) {
      int o = it * 4096 + tid * 16;
      int row = o >> 7;
      int gs = ((o >> 4) & 7) ^ (row & 7);
      gload_lds16(A + (size_t)(brow + row) * K + k0 + gs * 8, As + o);
      gload_lds16(B + (size_t)(bcol + row) * K + k0 + gs * 8, Bs + o);
    }
    __syncthreads();
#pragma unroll
    for (int ks = 0; ks < 2; ++ks) {
      bf16x8 af[4], bfr[4];
#pragma unroll
      for (int m = 0; m < 4; ++m) {
        int ra = wr + m * 16 + lr;
        af[m] = *(const bf16x8*)(As + ra * 128 + (((ks * 4 + lg) ^ (ra & 7)) << 4));
        int rb = wc + m * 16 + lr;
        bfr[m] = *(const bf16x8*)(Bs + rb * 128 + (((ks * 4 + lg) ^ (rb & 7)) << 4));
      }
#pragma unroll
      for (int m = 0; m < 4; ++m)
#pragma unroll
        for (int n = 0; n < 4; ++n)
          acc[m][n] = __builtin_amdgcn_mfma_f32_16x16x32_bf16(af[m], bfr[n], acc[m][n], 0, 0, 0);
    }
    __syncthreads();
  }
#pragma unroll
  for (int m = 0; m < 4; ++m) {
    int row = brow + wr + m * 16 + lg * 4;
#pragma unroll
    for (int n = 0; n < 4; ++n) {
      int col = bcol + wc + n * 16 + lr;
      float bv = bias[col];
#pragma unroll
      for (int i = 0; i < 4; ++i) C[(size_t)(row + i) * N + col] = acc[m][n][i] + bv;
    }
  }
}

// ---------------- qkv post: RMS(head) [+RoPE] -> Q/K/V bf16 [h][ntot][128] ----------------
// one wave per (n,h); lane i handles pair (2i, 2i+1)
__global__ __launch_bounds__(256) void k_post(const float* __restrict__ qkv,
                                              const float* __restrict__ wq,
                                              const float* __restrict__ wk,
                                              const float* __restrict__ cosb,
                                              const float* __restrict__ sinb,
                                              short* __restrict__ Qb, short* __restrict__ Kb,
                                              short* __restrict__ Vb, int ntot_base) {
  int idx = blockIdx.x * 4 + (threadIdx.x >> 6);
  int l = threadIdx.x & 63;
  int n = idx / 24, h = idx - n * 24;
  const float* base = qkv + (size_t)n * 9216 + h * 128;
  float2 q = *(const float2*)(base + 2 * l);
  float2 k = *(const float2*)(base + 3072 + 2 * l);
  float2 v = *(const float2*)(base + 6144 + 2 * l);
  float sq = q.x * q.x + q.y * q.y;
  float sk = k.x * k.x + k.y * k.y;
#pragma unroll
  for (int m = 1; m < 64; m <<= 1) {
    sq += __shfl_xor(sq, m);
    sk += __shfl_xor(sk, m);
  }
  float rq = rsqrtf(sq * (1.f / 128.f) + 1e-5f);
  float rk = rsqrtf(sk * (1.f / 128.f) + 1e-5f);
  float2 wqv = *(const float2*)(wq + 2 * l);
  float2 wkv = *(const float2*)(wk + 2 * l);
  float qx = q.x * rq * wqv.x, qy = q.y * rq * wqv.y;
  float kx = k.x * rk * wkv.x, ky = k.y * rk * wkv.y;
  if (cosb) {
    float c = cosb[(size_t)idx * 64 + l];
    float s = sinb[(size_t)idx * 64 + l];
    float t;
    t = qx * c - qy * s; qy = qx * s + qy * c; qx = t;
    t = kx * c - ky * s; ky = kx * s + ky * c; kx = t;
  }
  size_t off = ((size_t)h * NTOT + ntot_base + n) * 128 + 2 * l;
  *(unsigned*)(Qb + off) = pack2(qx, qy);
  *(unsigned*)(Kb + off) = pack2(kx, ky);
  *(unsigned*)(Vb + off) = pack2(v.x, v.y);
}

// ---------------- V [h][n][128] -> VT [h][128][n] ----------------
__global__ __launch_bounds__(256) void k_transpose(const short* __restrict__ V,
                                                   short* __restrict__ VT) {
  __shared__ __align__(16) short tile[64][72];
  int h = blockIdx.z;
  int n0 = blockIdx.x * 64, d0 = blockIdx.y * 64;
  int tid = threadIdx.x;
#pragma unroll
  for (int it = 0; it < 2; ++it) {
    int nl = it * 32 + (tid >> 3);
    int dl = (tid & 7) * 8;
    *(bf16x8*)&tile[nl][dl] = *(const bf16x8*)(V + ((size_t)h * NTOT + n0 + nl) * 128 + d0 + dl);
  }
  __syncthreads();
#pragma unroll
  for (int it = 0; it < 2; ++it) {
    int dl = it * 32 + (tid >> 3);
    int nl = (tid & 7) * 8;
    bf16x8 o;
#pragma unroll
    for (int j = 0; j < 8; ++j) o[j] = tile[nl + j][dl];
    *(bf16x8*)(VT + ((size_t)h * 128 + d0 + dl) * NTOT + n0 + nl) = o;
  }
}

// ---------------- flash attention, BQ=64 (4 waves x 16 rows), BKV=64 ----------------
__global__ __launch_bounds__(256) void k_attn(const short* __restrict__ Qb,
                                              const short* __restrict__ Kb,
                                              const short* __restrict__ VT,
                                              const int* __restrict__ seqlens,
                                              short* __restrict__ Ob) {
  __shared__ __align__(16) char Ks[16384];
  __shared__ __align__(16) char Vs[16384];
  __shared__ __align__(16) char Ps[4 * 2816];
  const int tid = threadIdx.x;
  const int w = tid >> 6, l = tid & 63;
  const int lr = l & 15, lg = l >> 4;
  const int h = blockIdx.y;
  const int q0 = blockIdx.x * 64 + w * 16;
  const size_t hK = (size_t)h * NTOT * 128;
  const size_t hV = (size_t)h * 128 * NTOT;
  bf16x8 qf[4];
#pragma unroll
  for (int kd = 0; kd < 4; ++kd)
    qf[kd] = *(const bf16x8*)(Qb + hK + (size_t)(q0 + lr) * 128 + kd * 32 + lg * 8);
  f32x4 acc[8];
#pragma unroll
  for (int n = 0; n < 8; ++n) acc[n] = (f32x4){0.f, 0.f, 0.f, 0.f};
  float mrow[4], lsum[4];
#pragma unroll
  for (int i = 0; i < 4; ++i) { mrow[i] = -1e30f; lsum[i] = 0.f; }
  const int kvlim = 2048 + seqlens[0];
  const int ntiles = (kvlim + 63) >> 6;
  char* Pw = Ps + w * 2816;
  const float sscale = 0.08838834764831845f;  // 1/sqrt(128)
  for (int t = 0; t < ntiles; ++t) {
    int kv0 = t * 64;
#pragma unroll
    for (int it = 0; it < 4; ++it) {
      int o = it * 4096 + tid * 16;
      int rk = o >> 8;
      int gk = ((o >> 4) & 15) ^ (rk & 7);
      gload_lds16(Kb + hK + (size_t)(kv0 + rk) * 128 + gk * 8, Ks + o);
      int rv = o >> 7;
      int gv = ((o >> 4) & 7) ^ (rv & 7);
      gload_lds16(VT + hV + (size_t)rv * NTOT + kv0 + gv * 8, Vs + o);
    }
    __syncthreads();
    f32x4 s[4];
#pragma unroll
    for (int c = 0; c < 4; ++c) {
      f32x4 sc = (f32x4){0.f, 0.f, 0.f, 0.f};
      int r = c * 16 + lr;
#pragma unroll
      for (int kd = 0; kd < 4; ++kd) {
        bf16x8 kf = *(const bf16x8*)(Ks + r * 256 + (((kd * 4 + lg) ^ (r & 7)) << 4));
        sc = __builtin_amdgcn_mfma_f32_16x16x32_bf16(qf[kd], kf, sc, 0, 0, 0);
      }
      s[c] = sc;
    }
#pragma unroll
    for (int c = 0; c < 4; ++c) {
      int col = kv0 + c * 16 + lr;
#pragma unroll
      for (int i = 0; i < 4; ++i) s[c][i] = (col < kvlim) ? s[c][i] * sscale : -1e30f;
    }
    float corr[4];
#pragma unroll
    for (int i = 0; i < 4; ++i) {
      float v = fmaxf(fmaxf(s[0][i], s[1][i]), fmaxf(s[2][i], s[3][i]));
      v = fmaxf(v, __shfl_xor(v, 1));
      v = fmaxf(v, __shfl_xor(v, 2));
      v = fmaxf(v, __shfl_xor(v, 4));
      v = fmaxf(v, __shfl_xor(v, 8));
      float mn = fmaxf(mrow[i], v);
      corr[i] = __expf(mrow[i] - mn);
      mrow[i] = mn;
    }
    float rs[4] = {0.f, 0.f, 0.f, 0.f};
#pragma unroll
    for (int c = 0; c < 4; ++c)
#pragma unroll
      for (int i = 0; i < 4; ++i) {
        float p = __expf(s[c][i] - mrow[i]);
        s[c][i] = p;
        rs[i] += p;
      }
#pragma unroll
    for (int i = 0; i < 4; ++i) {
      float v = rs[i];
      v += __shfl_xor(v, 1);
      v += __shfl_xor(v, 2);
      v += __shfl_xor(v, 4);
      v += __shfl_xor(v, 8);
      lsum[i] = lsum[i] * corr[i] + v;
    }
#pragma unroll
    for (int n = 0; n < 8; ++n)
#pragma unroll
      for (int i = 0; i < 4; ++i) acc[n][i] *= corr[i];
    // P -> per-wave LDS (stride 88 bf16 rows to spread banks)
#pragma unroll
    for (int c = 0; c < 4; ++c)
#pragma unroll
      for (int i = 0; i < 4; ++i)
        *(short*)(Pw + (lg * 4 + i) * 176 + (c * 16 + lr) * 2) = (short)f2bf(s[c][i]);
#pragma unroll
    for (int ks = 0; ks < 2; ++ks) {
      bf16x8 pa = *(const bf16x8*)(Pw + lr * 176 + ks * 64 + lg * 16);
#pragma unroll
      for (int n = 0; n < 8; ++n) {
        int r = n * 16 + lr;
        bf16x8 vb = *(const bf16x8*)(Vs + r * 128 + (((ks * 4 + lg) ^ (r & 7)) << 4));
        acc[n] = __builtin_amdgcn_mfma_f32_16x16x32_bf16(pa, vb, acc[n], 0, 0, 0);
      }
    }
    __syncthreads();
  }
#pragma unroll
  for (int i = 0; i < 4; ++i) {
    int q = q0 + lg * 4 + i;
    float inv = 1.f / lsum[i];
    bool valid = q < kvlim;
#pragma unroll
    for (int n = 0; n < 8; ++n) {
      float v = valid ? acc[n][i] * inv : 0.f;
      Ob[(size_t)q * 3072 + h * 128 + n * 16 + lr] = (short)f2bf(v);
    }
  }
}

extern "C" void kernel_launch(void* const* d_in, const int* in_sizes, int n_in,
                              void* d_out, int out_size, void* d_ws, size_t ws_size,
                              hipStream_t stream) {
  const float* x       = (const float*)d_in[0];
  const float* y       = (const float*)d_in[1];
  const float* scale_x = (const float*)d_in[2];
  const float* scale_y = (const float*)d_in[3];
  const float* ropec   = (const float*)d_in[4];
  const float* ropes   = (const float*)d_in[5];
  const int*   seqlens = (const int*)d_in[6];
  const float* Wqx     = (const float*)d_in[7];
  const float* bqx     = (const float*)d_in[8];
  const float* Wqy     = (const float*)d_in[9];
  const float* bqy     = (const float*)d_in[10];
  const float* wqnx    = (const float*)d_in[11];
  const float* wknx    = (const float*)d_in[12];
  const float* wqny    = (const float*)d_in[13];
  const float* wkny    = (const float*)d_in[14];
  const float* Wpx     = (const float*)d_in[15];
  const float* bpx     = (const float*)d_in[16];
  const float* Wpy     = (const float*)d_in[17];
  const float* bpy     = (const float*)d_in[18];
  float* out = (float*)d_out;
  (void)in_sizes; (void)n_in; (void)out_size; (void)ws_size;

  char* ws = (char*)d_ws;
  size_t off = 0;
  auto alloc = [&](size_t bytes) {
    char* p = ws + off;
    off += (bytes + 255) & ~(size_t)255;
    return p;
  };
  short* xm   = (short*)alloc((size_t)2048 * 3072 * 2);
  short* ym   = (short*)alloc((size_t)256 * 1536 * 2);
  short* wqxb = (short*)alloc((size_t)9216 * 3072 * 2);
  short* wqyb = (short*)alloc((size_t)9216 * 1536 * 2);
  short* wpxb = (short*)alloc((size_t)3072 * 3072 * 2);
  short* wpyb = (short*)alloc((size_t)1536 * 3072 * 2);
  float* qkvx = (float*)alloc((size_t)2048 * 9216 * 4);
  float* qkvy = (float*)alloc((size_t)256 * 9216 * 4);
  short* Qb   = (short*)alloc((size_t)24 * NTOT * 128 * 2);
  short* Kb   = (short*)alloc((size_t)24 * NTOT * 128 * 2);
  short* Vb   = (short*)alloc((size_t)24 * NTOT * 128 * 2);
  short* VTb  = (short*)alloc((size_t)24 * NTOT * 128 * 2);
  short* AO   = (short*)alloc((size_t)NTOT * 3072 * 2);

  hipLaunchKernelGGL(k_modnorm, dim3(2048), dim3(256), 0, stream, x, scale_x, xm, 3072, 1e-6f);
  hipLaunchKernelGGL(k_modnorm, dim3(256), dim3(256), 0, stream, y, scale_y, ym, 1536, 1e-6f);
  hipLaunchKernelGGL(k_cvt, dim3(2048), dim3(256), 0, stream, Wqx, wqxb, 9216 * 3072 / 4);
  hipLaunchKernelGGL(k_cvt, dim3(2048), dim3(256), 0, stream, Wqy, wqyb, 9216 * 1536 / 4);
  hipLaunchKernelGGL(k_cvt, dim3(2048), dim3(256), 0, stream, Wpx, wpxb, 3072 * 3072 / 4);
  hipLaunchKernelGGL(k_cvt, dim3(1024), dim3(256), 0, stream, Wpy, wpyb, 1536 * 3072 / 4);
  hipLaunchKernelGGL(k_gemm, dim3(72, 16), dim3(256), 0, stream, xm, wqxb, bqx, qkvx, 2048, 9216, 3072);
  hipLaunchKernelGGL(k_gemm, dim3(72, 2), dim3(256), 0, stream, ym, wqyb, bqy, qkvy, 256, 9216, 1536);
  hipLaunchKernelGGL(k_post, dim3(12288), dim3(256), 0, stream, qkvx, wqnx, wknx, ropec, ropes, Qb, Kb, Vb, 0);
  hipLaunchKernelGGL(k_post, dim3(1536), dim3(256), 0, stream, qkvy, wqny, wkny,
                     (const float*)nullptr, (const float*)nullptr, Qb, Kb, Vb, 2048);
  hipLaunchKernelGGL(k_transpose, dim3(36, 2, 24), dim3(256), 0, stream, Vb, VTb);
  hipLaunchKernelGGL(k_attn, dim3(36, 24), dim3(256), 0, stream, Qb, Kb, VTb, seqlens, AO);
  hipLaunchKernelGGL(k_gemm, dim3(24, 16), dim3(256), 0, stream, AO, wpxb, bpx, out, 2048, 3072, 3072);
  hipLaunchKernelGGL(k_gemm, dim3(12, 2), dim3(256), 0, stream, AO + (size_t)2048 * 3072, wpyb, bpy,
                     out + (size_t)2048 * 3072, 256, 1536, 3072);
}

// Round 2
// 546.507 us; speedup vs baseline: 1.2109x; 1.2109x over previous
//
#include <hip/hip_runtime.h>
#include <stdint.h>

#define DEV __device__ __forceinline__

typedef __attribute__((ext_vector_type(8))) short bf16x8;
typedef __attribute__((ext_vector_type(4))) float f32x4;
typedef __attribute__((ext_vector_type(16))) float f32x16;
typedef __attribute__((ext_vector_type(4))) unsigned u32x4;

#define NTOT 2304

DEV unsigned short f2bf(float f) {
  union { float f; unsigned u; } c; c.f = f;
  return (unsigned short)((c.u + 0x7FFFu + ((c.u >> 16) & 1u)) >> 16);
}
DEV unsigned pack2(float lo, float hi) {
  return ((unsigned)f2bf(hi) << 16) | (unsigned)f2bf(lo);
}
DEV float bf2f(short x) {
  union { unsigned u; float f; } c; c.u = ((unsigned)(unsigned short)x) << 16; return c.f;
}
DEV void gload_lds16(const void* g, void* l) {
  __builtin_amdgcn_global_load_lds(
      (const __attribute__((address_space(1))) unsigned int*)g,
      (__attribute__((address_space(3))) unsigned int*)l, 16, 0, 0);
}
DEV void pl32swap(unsigned& a, unsigned& b) {
  asm volatile("v_permlane32_swap_b32 %0, %1" : "+v"(a), "+v"(b));
}

// ---------------- RMS-modulated norm ----------------
__global__ __launch_bounds__(256) void k_modnorm(const float* __restrict__ X,
                                                 const float* __restrict__ scale,
                                                 short* __restrict__ out, int D, float eps) {
  int row = blockIdx.x;
  const float* x = X + (size_t)row * D;
  float ss = 0.f;
  for (int v = threadIdx.x * 4; v < D; v += 1024) {
    float4 a = *(const float4*)(x + v);
    ss += a.x * a.x + a.y * a.y + a.z * a.z + a.w * a.w;
  }
#pragma unroll
  for (int m = 1; m < 64; m <<= 1) ss += __shfl_xor(ss, m);
  __shared__ float red[4];
  if ((threadIdx.x & 63) == 0) red[threadIdx.x >> 6] = ss;
  __syncthreads();
  float tot = red[0] + red[1] + red[2] + red[3];
  float r = rsqrtf(tot / (float)D + eps);
  short* o = out + (size_t)row * D;
  for (int v = threadIdx.x * 4; v < D; v += 1024) {
    float4 a = *(const float4*)(x + v);
    float4 s = *(const float4*)(scale + v);
    uint2 pk;
    pk.x = pack2(a.x * r * (1.f + s.x), a.y * r * (1.f + s.y));
    pk.y = pack2(a.z * r * (1.f + s.z), a.w * r * (1.f + s.w));
    *(uint2*)(o + v) = pk;
  }
}

// ---------------- f32 -> bf16 convert ----------------
__global__ __launch_bounds__(256) void k_cvt(const float* __restrict__ in,
                                             short* __restrict__ out, int n4) {
  int stride = gridDim.x * blockDim.x;
  for (int i = blockIdx.x * blockDim.x + threadIdx.x; i < n4; i += stride) {
    float4 a = *(const float4*)(in + (size_t)i * 4);
    uint2 pk;
    pk.x = pack2(a.x, a.y);
    pk.y = pack2(a.z, a.w);
    *(uint2*)(out + (size_t)i * 4) = pk;
  }
}

// ---------------- C_f32[M][N] = A_bf16[M][K] @ B_bf16[N][K]^T + bias[N] ----------------
__global__ __launch_bounds__(256) void k_gemm(const short* __restrict__ A,
                                              const short* __restrict__ B,
                                              const float* __restrict__ bias,
                                              float* __restrict__ C, int M, int N, int K) {
  __shared__ __align__(16) char As[16384];
  __shared__ __align__(16) char Bs[16384];
  const int tid = threadIdx.x;
  const int brow = blockIdx.y * 128, bcol = blockIdx.x * 128;
  const int w = tid >> 6, l = tid & 63;
  const int wr = (w >> 1) * 64, wc = (w & 1) * 64;
  const int lr = l & 15, lg = l >> 4;
  f32x4 acc[4][4];
#pragma unroll
  for (int m = 0; m < 4; ++m)
#pragma unroll
    for (int n = 0; n < 4; ++n) acc[m][n] = (f32x4){0.f, 0.f, 0.f, 0.f};
  for (int k0 = 0; k0 < K; k0 += 64) {
#pragma unroll
    for (int it = 0; it < 4; ++it) {
      int o = it * 4096 + tid * 16;
      int row = o >> 7;
      int gs = ((o >> 4) & 7) ^ (row & 7);
      gload_lds16(A + (size_t)(brow + row) * K + k0 + gs * 8, As + o);
      gload_lds16(B + (size_t)(bcol + row) * K + k0 + gs * 8, Bs + o);
    }
    __syncthreads();
#pragma unroll
    for (int ks = 0; ks < 2; ++ks) {
      bf16x8 af[4], bfr[4];
#pragma unroll
      for (int m = 0; m < 4; ++m) {
        int ra = wr + m * 16 + lr;
        af[m] = *(const bf16x8*)(As + ra * 128 + (((ks * 4 + lg) ^ (ra & 7)) << 4));
        int rb = wc + m * 16 + lr;
        bfr[m] = *(const bf16x8*)(Bs + rb * 128 + (((ks * 4 + lg) ^ (rb & 7)) << 4));
      }
#pragma unroll
      for (int m = 0; m < 4; ++m)
#pragma unroll
        for (int n = 0; n < 4; ++n)
          acc[m][n] = __builtin_amdgcn_mfma_f32_16x16x32_bf16(af[m], bfr[n], acc[m][n], 0, 0, 0);
    }
    __syncthreads();
  }
#pragma unroll
  for (int m = 0; m < 4; ++m) {
    int row = brow + wr + m * 16 + lg * 4;
#pragma unroll
    for (int n = 0; n < 4; ++n) {
      int col = bcol + wc + n * 16 + lr;
      float bv = bias[col];
#pragma unroll
      for (int i = 0; i < 4; ++i) C[(size_t)(row + i) * N + col] = acc[m][n][i] + bv;
    }
  }
}

// ---------------- qkv post: RMS(head) [+RoPE] ----------------
__global__ __launch_bounds__(256) void k_post(const float* __restrict__ qkv,
                                              const float* __restrict__ wq,
                                              const float* __restrict__ wk,
                                              const float* __restrict__ cosb,
                                              const float* __restrict__ sinb,
                                              short* __restrict__ Qb, short* __restrict__ Kb,
                                              short* __restrict__ Vb, int ntot_base) {
  int idx = blockIdx.x * 4 + (threadIdx.x >> 6);
  int l = threadIdx.x & 63;
  int n = idx / 24, h = idx - n * 24;
  const float* base = qkv + (size_t)n * 9216 + h * 128;
  float2 q = *(const float2*)(base + 2 * l);
  float2 k = *(const float2*)(base + 3072 + 2 * l);
  float2 v = *(const float2*)(base + 6144 + 2 * l);
  float sq = q.x * q.x + q.y * q.y;
  float sk = k.x * k.x + k.y * k.y;
#pragma unroll
  for (int m = 1; m < 64; m <<= 1) {
    sq += __shfl_xor(sq, m);
    sk += __shfl_xor(sk, m);
  }
  float rq = rsqrtf(sq * (1.f / 128.f) + 1e-5f);
  float rk = rsqrtf(sk * (1.f / 128.f) + 1e-5f);
  float2 wqv = *(const float2*)(wq + 2 * l);
  float2 wkv = *(const float2*)(wk + 2 * l);
  float qx = q.x * rq * wqv.x, qy = q.y * rq * wqv.y;
  float kx = k.x * rk * wkv.x, ky = k.y * rk * wkv.y;
  if (cosb) {
    float c = cosb[(size_t)idx * 64 + l];
    float s = sinb[(size_t)idx * 64 + l];
    float t;
    t = qx * c - qy * s; qy = qx * s + qy * c; qx = t;
    t = kx * c - ky * s; ky = kx * s + ky * c; kx = t;
  }
  size_t off = ((size_t)h * NTOT + ntot_base + n) * 128 + 2 * l;
  *(unsigned*)(Qb + off) = pack2(qx, qy);
  *(unsigned*)(Kb + off) = pack2(kx, ky);
  *(unsigned*)(Vb + off) = pack2(v.x, v.y);
}

// ---------------- V [h][n][128] -> VT [h][128][n] ----------------
__global__ __launch_bounds__(256) void k_transpose(const short* __restrict__ V,
                                                   short* __restrict__ VT) {
  __shared__ __align__(16) short tile[64][72];
  int h = blockIdx.z;
  int n0 = blockIdx.x * 64, d0 = blockIdx.y * 64;
  int tid = threadIdx.x;
#pragma unroll
  for (int it = 0; it < 2; ++it) {
    int nl = it * 32 + (tid >> 3);
    int dl = (tid & 7) * 8;
    *(bf16x8*)&tile[nl][dl] = *(const bf16x8*)(V + ((size_t)h * NTOT + n0 + nl) * 128 + d0 + dl);
  }
  __syncthreads();
#pragma unroll
  for (int it = 0; it < 2; ++it) {
    int dl = it * 32 + (tid >> 3);
    int nl = (tid & 7) * 8;
    bf16x8 o;
#pragma unroll
    for (int j = 0; j < 8; ++j) o[j] = tile[nl + j][dl];
    *(bf16x8*)(VT + ((size_t)h * 128 + d0 + dl) * NTOT + n0 + nl) = o;
  }
}

// ---------------- flash attention, 32x32 MFMA, swapped QK^T, in-register softmax ----------
// 4 waves x 32 q-rows = 128 q per block. Per lane: q = lane&31 (column of S^T).
__global__ __launch_bounds__(256, 2) void k_attn32(const short* __restrict__ Qb,
                                                   const short* __restrict__ Kb,
                                                   const short* __restrict__ VT,
                                                   const int* __restrict__ seqlens,
                                                   short* __restrict__ Ob) {
  __shared__ __align__(16) char lds[65536];  // 2 x (K 16K | VT 16K); epilogue reuses 32K
  const int tid = threadIdx.x;
  const int w = tid >> 6, l = tid & 63;
  const int l31 = l & 31, hi = l >> 5;
  // bijective XCD swizzle: 432 = 8*54, 54 = 3 heads * 18 q-blocks per XCD
  int orig = blockIdx.x;
  int wg = (orig & 7) * 54 + (orig >> 3);
  int h = wg / 18, qb = wg - h * 18;
  const int q0 = qb * 128;
  const size_t hK = (size_t)h * NTOT * 128;
  const size_t hV = (size_t)h * 128 * NTOT;
  const int kvlim = 2048 + seqlens[0];
  const int nt = (kvlim + 63) >> 6;

  // Q fragments (B-operand: col j = q = lane&31, k = hi*8+e), prescaled by 1/sqrt(128)
  const float qs = 0.08838834764831845f;
  bf16x8 qf[8];
  {
    const short* qrow = Qb + hK + (size_t)(q0 + w * 32 + l31) * 128;
#pragma unroll
    for (int s = 0; s < 8; ++s) {
      bf16x8 r = *(const bf16x8*)(qrow + s * 16 + hi * 8);
      union { unsigned u[4]; bf16x8 b; } cv;
#pragma unroll
      for (int d = 0; d < 4; ++d)
        cv.u[d] = pack2(bf2f(r[2 * d]) * qs, bf2f(r[2 * d + 1]) * qs);
      qf[s] = cv.b;
    }
  }

  f32x16 acc[4];
#pragma unroll
  for (int d0 = 0; d0 < 4; ++d0)
#pragma unroll
    for (int r = 0; r < 16; ++r) acc[d0][r] = 0.f;
  float mrun = -1e30f, lsum = 0.f;

  // stage kv-tile t into buffer buf (pre-swizzled global source, linear LDS dest)
  auto stage = [&](int t, int buf) {
    int kv0 = t * 64;
    char* bK = lds + buf * 32768;
    char* bV = bK + 16384;
#pragma unroll
    for (int it = 0; it < 4; ++it) {
      int o = it * 4096 + tid * 16;
      int rk = o >> 8, sk = (o >> 4) & 15;
      gload_lds16(Kb + hK + (size_t)(kv0 + rk) * 128 + (sk ^ (rk & 7)) * 8, bK + o);
      int rv = o >> 7, sv = (o >> 4) & 7;
      gload_lds16(VT + hV + (size_t)rv * NTOT + kv0 + (sv ^ (rv & 7)) * 8, bV + o);
    }
  };

  stage(0, 0);
  asm volatile("s_waitcnt vmcnt(0)");
  __syncthreads();

  int cur = 0;
  for (int t = 0; t < nt; ++t) {
    if (t + 1 < nt) stage(t + 1, cur ^ 1);
    const char* bK = lds + cur * 32768;
    const char* bV = bK + 16384;
    // S^T = K . Q^T  (rows = kv, cols = q)
    f32x16 st[2];
#pragma unroll
    for (int hf = 0; hf < 2; ++hf)
#pragma unroll
      for (int r = 0; r < 16; ++r) st[hf][r] = 0.f;
#pragma unroll
    for (int hf = 0; hf < 2; ++hf) {
      int row = hf * 32 + l31;
      int rx = row & 7;
#pragma unroll
      for (int s = 0; s < 8; ++s) {
        bf16x8 kf = *(const bf16x8*)(bK + row * 256 + (((s * 2 + hi) ^ rx) << 4));
        st[hf] = __builtin_amdgcn_mfma_f32_32x32x16_bf16(kf, qf[s], st[hf], 0, 0, 0);
      }
    }
    // mask tail
    if (t == nt - 1) {
      int kv0 = t * 64;
#pragma unroll
      for (int hf = 0; hf < 2; ++hf)
#pragma unroll
        for (int r = 0; r < 16; ++r) {
          int kv = kv0 + hf * 32 + (r & 3) + 8 * (r >> 2) + 4 * hi;
          if (kv >= kvlim) st[hf][r] = -1e30f;
        }
    }
    // per-q max: 31 in-lane + 1 cross (lane^32 holds the other 32 kv rows)
    float tmax = st[0][0];
#pragma unroll
    for (int r = 1; r < 16; ++r) tmax = fmaxf(tmax, st[0][r]);
#pragma unroll
    for (int r = 0; r < 16; ++r) tmax = fmaxf(tmax, st[1][r]);
    tmax = fmaxf(tmax, __shfl_xor(tmax, 32));
    // defer-max (T13): rescale only when tile max grew past threshold
    if (!__all(tmax - mrun <= 8.0f)) {
      float mnew = fmaxf(mrun, tmax);
      float corr = __expf(mrun - mnew);
      mrun = mnew;
      lsum *= corr;
#pragma unroll
      for (int d0 = 0; d0 < 4; ++d0)
#pragma unroll
        for (int r = 0; r < 16; ++r) acc[d0][r] *= corr;
    }
    // P = exp(S - m), row-sum
    float ts = 0.f;
#pragma unroll
    for (int hf = 0; hf < 2; ++hf)
#pragma unroll
      for (int r = 0; r < 16; ++r) {
        float p = __expf(st[hf][r] - mrun);
        st[hf][r] = p;
        ts += p;
      }
    ts += __shfl_xor(ts, 32);
    lsum += ts;
    // P^T -> B-fragments via pack2 + permlane32_swap (T12)
    bf16x8 pa[4];
#pragma unroll
    for (int hf = 0; hf < 2; ++hf) {
      unsigned x0 = pack2(st[hf][0], st[hf][1]);
      unsigned y0 = pack2(st[hf][4], st[hf][5]);
      pl32swap(x0, y0);
      unsigned z0 = pack2(st[hf][2], st[hf][3]);
      unsigned w0 = pack2(st[hf][6], st[hf][7]);
      pl32swap(z0, w0);
      { union { u32x4 u; bf16x8 b; } cv; cv.u = (u32x4){x0, z0, y0, w0}; pa[hf * 2 + 0] = cv.b; }
      unsigned x1 = pack2(st[hf][8], st[hf][9]);
      unsigned y1 = pack2(st[hf][12], st[hf][13]);
      pl32swap(x1, y1);
      unsigned z1 = pack2(st[hf][10], st[hf][11]);
      unsigned w1 = pack2(st[hf][14], st[hf][15]);
      pl32swap(z1, w1);
      { union { u32x4 u; bf16x8 b; } cv; cv.u = (u32x4){x1, z1, y1, w1}; pa[hf * 2 + 1] = cv.b; }
    }
    // O^T += V^T . P^T
#pragma unroll
    for (int d0 = 0; d0 < 4; ++d0) {
      int row = d0 * 32 + l31;
      int rx = row & 7;
#pragma unroll
      for (int s4 = 0; s4 < 4; ++s4) {
        bf16x8 va = *(const bf16x8*)(bV + row * 128 + (((s4 * 2 + hi) ^ rx) << 4));
        acc[d0] = __builtin_amdgcn_mfma_f32_32x32x16_bf16(va, pa[s4], acc[d0], 0, 0, 0);
      }
    }
    asm volatile("s_waitcnt vmcnt(0)");
    __syncthreads();
    cur ^= 1;
  }

  // epilogue: O^T (lane-held) -> LDS (swizzled) -> coalesced bf16 store
  {
    char* ob = lds;
    int qloc = w * 32 + l31;
    int qg = q0 + qloc;
    float inv = (qg < kvlim) ? 1.f / lsum : 0.f;
#pragma unroll
    for (int d0 = 0; d0 < 4; ++d0)
#pragma unroll
      for (int g = 0; g < 4; ++g) {
        int dbase = d0 * 32 + 8 * g + 4 * hi;
        uint2 pk;
        pk.x = pack2(acc[d0][4 * g + 0] * inv, acc[d0][4 * g + 1] * inv);
        pk.y = pack2(acc[d0][4 * g + 2] * inv, acc[d0][4 * g + 3] * inv);
        int off = dbase * 2;
        int off2 = ((((off >> 4) ^ (qloc & 7)) << 4) | (off & 8));
        *(uint2*)(ob + qloc * 256 + off2) = pk;
      }
    __syncthreads();
    int qr = tid >> 1, dh = tid & 1;
#pragma unroll
    for (int j = 0; j < 8; ++j) {
      int slot = dh * 8 + j;
      bf16x8 v = *(const bf16x8*)(ob + qr * 256 + ((slot ^ (qr & 7)) << 4));
      *(bf16x8*)(Ob + (size_t)(q0 + qr) * 3072 + h * 128 + slot * 8) = v;
    }
  }
}

extern "C" void kernel_launch(void* const* d_in, const int* in_sizes, int n_in,
                              void* d_out, int out_size, void* d_ws, size_t ws_size,
                              hipStream_t stream) {
  const float* x       = (const float*)d_in[0];
  const float* y       = (const float*)d_in[1];
  const float* scale_x = (const float*)d_in[2];
  const float* scale_y = (const float*)d_in[3];
  const float* ropec   = (const float*)d_in[4];
  const float* ropes   = (const float*)d_in[5];
  const int*   seqlens = (const int*)d_in[6];
  const float* Wqx     = (const float*)d_in[7];
  const float* bqx     = (const float*)d_in[8];
  const float* Wqy     = (const float*)d_in[9];
  const float* bqy     = (const float*)d_in[10];
  const float* wqnx    = (const float*)d_in[11];
  const float* wknx    = (const float*)d_in[12];
  const float* wqny    = (const float*)d_in[13];
  const float* wkny    = (const float*)d_in[14];
  const float* Wpx     = (const float*)d_in[15];
  const float* bpx     = (const float*)d_in[16];
  const float* Wpy     = (const float*)d_in[17];
  const float* bpy     = (const float*)d_in[18];
  float* out = (float*)d_out;
  (void)in_sizes; (void)n_in; (void)out_size; (void)ws_size;

  char* ws = (char*)d_ws;
  size_t off = 0;
  auto alloc = [&](size_t bytes) {
    char* p = ws + off;
    off += (bytes + 255) & ~(size_t)255;
    return p;
  };
  short* xm   = (short*)alloc((size_t)2048 * 3072 * 2);
  short* ym   = (short*)alloc((size_t)256 * 1536 * 2);
  short* wqxb = (short*)alloc((size_t)9216 * 3072 * 2);
  short* wqyb = (short*)alloc((size_t)9216 * 1536 * 2);
  short* wpxb = (short*)alloc((size_t)3072 * 3072 * 2);
  short* wpyb = (short*)alloc((size_t)1536 * 3072 * 2);
  float* qkvx = (float*)alloc((size_t)2048 * 9216 * 4);
  float* qkvy = (float*)alloc((size_t)256 * 9216 * 4);
  short* Qb   = (short*)alloc((size_t)24 * NTOT * 128 * 2);
  short* Kb   = (short*)alloc((size_t)24 * NTOT * 128 * 2);
  short* Vb   = (short*)alloc((size_t)24 * NTOT * 128 * 2);
  short* VTb  = (short*)alloc((size_t)24 * NTOT * 128 * 2);
  short* AO   = (short*)alloc((size_t)NTOT * 3072 * 2);

  hipLaunchKernelGGL(k_modnorm, dim3(2048), dim3(256), 0, stream, x, scale_x, xm, 3072, 1e-6f);
  hipLaunchKernelGGL(k_modnorm, dim3(256), dim3(256), 0, stream, y, scale_y, ym, 1536, 1e-6f);
  hipLaunchKernelGGL(k_cvt, dim3(2048), dim3(256), 0, stream, Wqx, wqxb, 9216 * 3072 / 4);
  hipLaunchKernelGGL(k_cvt, dim3(2048), dim3(256), 0, stream, Wqy, wqyb, 9216 * 1536 / 4);
  hipLaunchKernelGGL(k_cvt, dim3(2048), dim3(256), 0, stream, Wpx, wpxb, 3072 * 3072 / 4);
  hipLaunchKernelGGL(k_cvt, dim3(1024), dim3(256), 0, stream, Wpy, wpyb, 1536 * 3072 / 4);
  hipLaunchKernelGGL(k_gemm, dim3(72, 16), dim3(256), 0, stream, xm, wqxb, bqx, qkvx, 2048, 9216, 3072);
  hipLaunchKernelGGL(k_gemm, dim3(72, 2), dim3(256), 0, stream, ym, wqyb, bqy, qkvy, 256, 9216, 1536);
  hipLaunchKernelGGL(k_post, dim3(12288), dim3(256), 0, stream, qkvx, wqnx, wknx, ropec, ropes, Qb, Kb, Vb, 0);
  hipLaunchKernelGGL(k_post, dim3(1536), dim3(256), 0, stream, qkvy, wqny, wkny,
                     (const float*)nullptr, (const float*)nullptr, Qb, Kb, Vb, 2048);
  hipLaunchKernelGGL(k_transpose, dim3(36, 2, 24), dim3(256), 0, stream, Vb, VTb);
  hipLaunchKernelGGL(k_attn32, dim3(432), dim3(256), 0, stream, Qb, Kb, VTb, seqlens, AO);
  hipLaunchKernelGGL(k_gemm, dim3(24, 16), dim3(256), 0, stream, AO, wpxb, bpx, out, 2048, 3072, 3072);
  hipLaunchKernelGGL(k_gemm, dim3(12, 2), dim3(256), 0, stream, AO + (size_t)2048 * 3072, wpyb, bpy,
                     out + (size_t)2048 * 3072, 256, 1536, 3072);
}